// Round 6
// baseline (252.889 us; speedup 1.0000x reference)
//
#include <hip/hip_runtime.h>
#include <math.h>

#define LQ 22223
#define NH 8
#define NL 4
#define NP 4
#define CDIM 256
#define MBLK 348              // ceil(LQ/64)
#define NBV  (MBLK * 4)       // v-GEMM blocks   (N=256)
#define NBOA (MBLK * 6)       // offattn blocks  (N=384)

typedef __attribute__((ext_vector_type(8))) short short8;
typedef __attribute__((ext_vector_type(4))) float f32x4;

__device__ __forceinline__ ushort f2bf(float f) {
    union { float f; unsigned u; } c; c.f = f;
    unsigned u = c.u;
    return (ushort)((u + 0x7fffu + ((u >> 16) & 1u)) >> 16);   // RNE
}
__device__ __forceinline__ float bflo(unsigned u) {
    union { unsigned u; float f; } c; c.u = u << 16; return c.f;
}
__device__ __forceinline__ float bfhi(unsigned u) {
    union { unsigned u; float f; } c; c.u = u & 0xffff0000u; return c.f;
}

// ---------------------------------------------------------------------------
// Transpose+convert weights fp32 [K=256][N] -> bf16 [N][K].
// Wt_oa = concat(W_off rows, W_attn rows); bcat = concat(b_off, b_attn).
// ---------------------------------------------------------------------------
__global__ __launch_bounds__(256) void convert_wt(
    const float* __restrict__ Wv, const float* __restrict__ Wo,
    const float* __restrict__ Wu, const float* __restrict__ Wa,
    const float* __restrict__ bo, const float* __restrict__ ba,
    ushort* __restrict__ Tv, ushort* __restrict__ Toa,
    ushort* __restrict__ Tu, float* __restrict__ bcat)
{
    int idx = blockIdx.x * 256 + threadIdx.x;
    if (idx >= 229376) {
        int b = idx - 229376;
        if (b < 384) bcat[b] = (b < 256) ? bo[b] : ba[b - 256];
        return;
    }
    const float* W; ushort* T; int N; int local;
    if      (idx < 65536)  { W = Wv; T = Tv;          N = 256; local = idx; }
    else if (idx < 131072) { W = Wo; T = Toa;         N = 256; local = idx - 65536; }
    else if (idx < 196608) { W = Wu; T = Tu;          N = 256; local = idx - 131072; }
    else                   { W = Wa; T = Toa + 65536; N = 128; local = idx - 196608; }
    int k = local & 255;
    int n = local >> 8;
    T[n * 256 + k] = f2bf(W[k * N + n]);
}

// ---------------------------------------------------------------------------
// Fused dual GEMM (one launch, 3480 blocks of 64x64 tile, BK=32):
//   blocks [0, NBV):        v_bf  = bf16(value @ Wt_val^T + b_val)   N=256
//   blocks [NBV, NBV+NBOA): offattn = query @ Wt_oa^T + bcat (fp32)  N=384
// A is fp32, converted to bf16 during LDS staging.
// ---------------------------------------------------------------------------
__global__ __launch_bounds__(256) void gemm_dual(
    const float* __restrict__ value, const ushort* __restrict__ Wtv,
    const float* __restrict__ bv, ushort* __restrict__ Cv,
    const float* __restrict__ query, const ushort* __restrict__ Wtoa,
    const float* __restrict__ boa, float* __restrict__ Coa)
{
    const int K = 256;
    __shared__ ushort As[64 * 40];
    __shared__ ushort Bs[64 * 40];

    int b = blockIdx.x;
    const float* A; const ushort* Bt; const float* bias;
    int N, bx, by; bool isv;
    if (b < NBV) {
        isv = true;  A = value; Bt = Wtv;  bias = bv;  N = 256;
        bx = b & 3;  by = b >> 2;
    } else {
        isv = false; b -= NBV; A = query; Bt = Wtoa; bias = boa; N = 384;
        bx = b % 6;  by = b / 6;
    }

    const int tid = threadIdx.x;
    const int w = tid >> 6;
    const int l = tid & 63;
    const int bm = by * 64;
    const int bn = bx * 64;

    const int r = tid >> 2;
    const int c = tid & 3;

    const int m_l  = (w << 4) + (l & 15);
    const int koff = (l >> 4) << 3;

    f32x4 acc[4] = {};

    for (int k0 = 0; k0 < K; k0 += 32) {
        short8 av = {0, 0, 0, 0, 0, 0, 0, 0};
        if (bm + r < LQ) {
            const float4 f0 = *reinterpret_cast<const float4*>(
                A + (size_t)(bm + r) * K + k0 + c * 8);
            const float4 f1 = *reinterpret_cast<const float4*>(
                A + (size_t)(bm + r) * K + k0 + c * 8 + 4);
            av[0] = (short)f2bf(f0.x); av[1] = (short)f2bf(f0.y);
            av[2] = (short)f2bf(f0.z); av[3] = (short)f2bf(f0.w);
            av[4] = (short)f2bf(f1.x); av[5] = (short)f2bf(f1.y);
            av[6] = (short)f2bf(f1.z); av[7] = (short)f2bf(f1.w);
        }
        const short8 bvv = *reinterpret_cast<const short8*>(
            Bt + (size_t)(bn + r) * K + k0 + c * 8);

        __syncthreads();
        *reinterpret_cast<short8*>(&As[r * 40 + c * 8]) = av;
        *reinterpret_cast<short8*>(&Bs[r * 40 + c * 8]) = bvv;
        __syncthreads();

        const short8 af = *reinterpret_cast<const short8*>(&As[m_l * 40 + koff]);
        #pragma unroll
        for (int t = 0; t < 4; ++t) {
            const short8 bf = *reinterpret_cast<const short8*>(
                &Bs[(t * 16 + (l & 15)) * 40 + koff]);
            acc[t] = __builtin_amdgcn_mfma_f32_16x16x32_bf16(af, bf, acc[t], 0, 0, 0);
        }
    }

    const int row0 = bm + (w << 4) + ((l >> 4) << 2);
    #pragma unroll
    for (int t = 0; t < 4; ++t) {
        const int col = bn + t * 16 + (l & 15);
        const float bs = bias[col];
        #pragma unroll
        for (int i = 0; i < 4; ++i) {
            const int row = row0 + i;
            if (row < LQ) {
                const float o = acc[t][i] + bs;
                if (isv) Cv[(size_t)row * 256 + col] = f2bf(o);
                else     Coa[(size_t)row * 384 + col] = o;
            }
        }
    }
}

// ---------------------------------------------------------------------------
// bf16 MFMA GEMM (64x64 tile): C[M,N] = A[M,256] @ Bt[N,256]^T + bias  (fp32)
// A is bf16. Used for the output projection.
// ---------------------------------------------------------------------------
__global__ __launch_bounds__(256) void gemm_out(
    const ushort* __restrict__ A, const ushort* __restrict__ Bt,
    const float* __restrict__ bias, float* __restrict__ C)
{
    const int K = 256, N = 256;
    __shared__ ushort As[64 * 40];
    __shared__ ushort Bs[64 * 40];

    const int tid = threadIdx.x;
    const int w = tid >> 6;
    const int l = tid & 63;
    const int bm = blockIdx.y * 64;
    const int bn = blockIdx.x * 64;

    const int r = tid >> 2;
    const int c = tid & 3;

    const int m_l  = (w << 4) + (l & 15);
    const int koff = (l >> 4) << 3;

    f32x4 acc[4] = {};

    for (int k0 = 0; k0 < K; k0 += 32) {
        short8 av = {0, 0, 0, 0, 0, 0, 0, 0};
        if (bm + r < LQ)
            av = *reinterpret_cast<const short8*>(A + (size_t)(bm + r) * K + k0 + c * 8);
        const short8 bvv = *reinterpret_cast<const short8*>(
            Bt + (size_t)(bn + r) * K + k0 + c * 8);

        __syncthreads();
        *reinterpret_cast<short8*>(&As[r * 40 + c * 8]) = av;
        *reinterpret_cast<short8*>(&Bs[r * 40 + c * 8]) = bvv;
        __syncthreads();

        const short8 af = *reinterpret_cast<const short8*>(&As[m_l * 40 + koff]);
        #pragma unroll
        for (int t = 0; t < 4; ++t) {
            const short8 bf = *reinterpret_cast<const short8*>(
                &Bs[(t * 16 + (l & 15)) * 40 + koff]);
            acc[t] = __builtin_amdgcn_mfma_f32_16x16x32_bf16(af, bf, acc[t], 0, 0, 0);
        }
    }

    const int row0 = bm + (w << 4) + ((l >> 4) << 2);
    #pragma unroll
    for (int t = 0; t < 4; ++t) {
        const int col = bn + t * 16 + (l & 15);
        const float bs = bias[col];
        #pragma unroll
        for (int i = 0; i < 4; ++i) {
            const int row = row0 + i;
            if (row < LQ) C[(size_t)row * N + col] = acc[t][i] + bs;
        }
    }
}

// ---------------------------------------------------------------------------
// Multi-scale deformable sampling over bf16 value, softmax folded into
// phase 1 (reads RAW logits; each (q,point) task redundantly computes the
// 16-wide softmax from L1-cached logits).
//   block = 64 q x 4 lanes (8 bf16 channels each), one head.
//   blockIdx.x = qg*8 + h -> head-pinned to XCDs (per-head slice 1.42 MB).
// __launch_bounds__(256, 8): force VGPR <= 64 (8 waves/SIMD) — rounds 4/5
// showed the compiler otherwise hoists loads to 132-144 VGPR, crossing the
// 128-VGPR cliff down to 2 waves/SIMD; this latency-bound kernel needs TLP.
// LDS 32 KB -> 5 blocks/CU = 20 waves/CU ceiling.
// ---------------------------------------------------------------------------
__global__ __launch_bounds__(256, 8) void msda_sample(
    const ushort* __restrict__ v, const float* __restrict__ offattn,
    const float* __restrict__ ref, ushort* __restrict__ outp)
{
    __shared__ int4   s_off[1024];   // [p*64 + qi], element offsets into v
    __shared__ float4 s_wts[1024];

    const int h = blockIdx.x & 7;
    const int qbase = (blockIdx.x >> 3) * 64;
    const int tid = threadIdx.x;

    const int Hs[4] = {100, 50, 25, 13};
    const int Ws[4] = {167, 84, 42, 21};
    const int starts[4] = {0, 16700, 20900, 21950};
    const int h32 = h * 32;

    // ---- Phase 1: coords + folded softmax ----
    for (int t2 = 0; t2 < 4; ++t2) {
        const int t = t2 * 256 + tid;     // = pi*64 + qi
        const int qi = t & 63;
        const int pi = t >> 6;            // 0..15
        const int q = qbase + qi;
        if (q < LQ) {
            const int l = pi >> 2;
            const int W = Ws[l], H = Hs[l];
            const float* refq = ref + (size_t)q * (NL * 4) + l * 4;
            const float cx = refq[0], cy = refq[1], rw = refq[2], rh = refq[3];
            const float* row = offattn + (size_t)q * 384;

            // softmax over this (q,h)'s 16 logits
            const float* lrow = row + 256 + h * 16;
            float lv[16];
            #pragma unroll
            for (int i = 0; i < 4; ++i) {
                const float4 f = *reinterpret_cast<const float4*>(lrow + i * 4);
                lv[i * 4 + 0] = f.x; lv[i * 4 + 1] = f.y;
                lv[i * 4 + 2] = f.z; lv[i * 4 + 3] = f.w;
            }
            float mx = lv[0];
            #pragma unroll
            for (int i = 1; i < 16; ++i) mx = fmaxf(mx, lv[i]);
            float sum = 0.f;
            #pragma unroll
            for (int i = 0; i < 16; ++i) { lv[i] = expf(lv[i] - mx); sum += lv[i]; }
            const float wgt = lv[pi] / sum;

            const float ox = row[h32 + pi * 2];
            const float oy = row[h32 + pi * 2 + 1];

            const float lx = cx + ox * 0.125f * rw;
            const float ly = cy + oy * 0.125f * rh;
            const float x = lx * (float)W - 0.5f;
            const float y = ly * (float)H - 0.5f;

            const float x0f = floorf(x);
            const float y0f = floorf(y);
            const int x0 = (int)x0f, y0 = (int)y0f;
            const float wx1 = x - x0f, wy1 = y - y0f;
            const float wx0 = 1.f - wx1, wy0 = 1.f - wy1;

            const bool xv0 = (x0 >= 0) && (x0 < W);
            const bool xv1 = (x0 + 1 >= 0) && (x0 + 1 < W);
            const bool yv0 = (y0 >= 0) && (y0 < H);
            const bool yv1 = (y0 + 1 >= 0) && (y0 + 1 < H);

            const int x0c = min(max(x0, 0), W - 1);
            const int x1c = min(max(x0 + 1, 0), W - 1);
            const int y0c = min(max(y0, 0), H - 1);
            const int y1c = min(max(y0 + 1, 0), H - 1);

            int4 ob;
            ob.x = ((starts[l] + y0c * W + x0c) << 8) + h32;
            ob.y = ((starts[l] + y0c * W + x1c) << 8) + h32;
            ob.z = ((starts[l] + y1c * W + x0c) << 8) + h32;
            ob.w = ((starts[l] + y1c * W + x1c) << 8) + h32;
            float4 wb;
            wb.x = (xv0 && yv0) ? wgt * wy0 * wx0 : 0.f;
            wb.y = (xv1 && yv0) ? wgt * wy0 * wx1 : 0.f;
            wb.z = (xv0 && yv1) ? wgt * wy1 * wx0 : 0.f;
            wb.w = (xv1 && yv1) ? wgt * wy1 * wx1 : 0.f;
            s_off[t] = ob;
            s_wts[t] = wb;
        }
    }
    __syncthreads();

    // ---- Phase 2: gather + accumulate ----
    const int qi = tid >> 2;          // 0..63
    const int dg = tid & 3;           // channel group (8 bf16)
    const int q = qbase + qi;
    if (q >= LQ) return;
    const int d8 = dg * 8;

    float acc[8] = {};

    #pragma unroll 2
    for (int p = 0; p < 16; ++p) {
        const int4   o = s_off[p * 64 + qi];
        const float4 w = s_wts[p * 64 + qi];
        const uint4 a0 = *reinterpret_cast<const uint4*>(v + o.x + d8);
        const uint4 a1 = *reinterpret_cast<const uint4*>(v + o.y + d8);
        const uint4 a2 = *reinterpret_cast<const uint4*>(v + o.z + d8);
        const uint4 a3 = *reinterpret_cast<const uint4*>(v + o.w + d8);
        const unsigned u0[4] = {a0.x, a0.y, a0.z, a0.w};
        const unsigned u1[4] = {a1.x, a1.y, a1.z, a1.w};
        const unsigned u2[4] = {a2.x, a2.y, a2.z, a2.w};
        const unsigned u3[4] = {a3.x, a3.y, a3.z, a3.w};
        #pragma unroll
        for (int j = 0; j < 4; ++j) {
            acc[2 * j]     += w.x * bflo(u0[j]) + w.y * bflo(u1[j])
                            + w.z * bflo(u2[j]) + w.w * bflo(u3[j]);
            acc[2 * j + 1] += w.x * bfhi(u0[j]) + w.y * bfhi(u1[j])
                            + w.z * bfhi(u2[j]) + w.w * bfhi(u3[j]);
        }
    }

    short8 o8;
    #pragma unroll
    for (int j = 0; j < 8; ++j) o8[j] = (short)f2bf(acc[j]);
    *reinterpret_cast<short8*>(outp + (size_t)q * CDIM + h32 + d8) = o8;
}

// ---------------------------------------------------------------------------
extern "C" void kernel_launch(void* const* d_in, const int* in_sizes, int n_in,
                              void* d_out, int out_size, void* d_ws, size_t ws_size,
                              hipStream_t stream)
{
    const float* query  = (const float*)d_in[0];
    const float* ref    = (const float*)d_in[1];
    const float* value  = (const float*)d_in[2];
    const float* W_off  = (const float*)d_in[3];
    const float* b_off  = (const float*)d_in[4];
    const float* W_attn = (const float*)d_in[5];
    const float* b_attn = (const float*)d_in[6];
    const float* W_val  = (const float*)d_in[7];
    const float* b_val  = (const float*)d_in[8];
    const float* W_out  = (const float*)d_in[9];
    const float* b_out  = (const float*)d_in[10];
    float* out = (float*)d_out;

    char* p = (char*)d_ws;
    ushort* v_bf    = (ushort*)p; p += (size_t)LQ * CDIM * 2;   // bf16 value'
    float*  offattn = (float*)p;  p += (size_t)LQ * 384 * 4;    // raw logits inside
    ushort* outp    = (ushort*)p; p += (size_t)LQ * CDIM * 2;   // bf16 sampled
    ushort* Wt_val  = (ushort*)p; p += 65536 * 2;
    ushort* Wt_oa   = (ushort*)p; p += (65536 + 32768) * 2;
    ushort* Wt_out  = (ushort*)p; p += 65536 * 2;
    float*  bcat    = (float*)p;  p += 384 * 4;

    // 1. weights fp32 -> bf16 [N][K] (+ concatenated off/attn bias)
    convert_wt<<<(229376 + 384 + 255) / 256, 256, 0, stream>>>(
        W_val, W_off, W_out, W_attn, b_off, b_attn, Wt_val, Wt_oa, Wt_out, bcat);

    // 2. fused: v_bf = bf16(value@Wv + bv)  AND  offattn = query@Woa + bcat
    gemm_dual<<<NBV + NBOA, 256, 0, stream>>>(
        value, Wt_val, b_val, v_bf, query, Wt_oa, bcat, offattn);

    // 3. deformable sampling (softmax folded in) -> outp (bf16)
    const int qg = (LQ + 63) / 64;    // 348
    msda_sample<<<qg * 8, 256, 0, stream>>>(v_bf, offattn, ref, outp);

    // 4. out = outp @ W_out + b_out
    gemm_out<<<dim3(4, MBLK), 256, 0, stream>>>(outp, Wt_out, b_out, out);
}

// Round 7
// 216.758 us; speedup vs baseline: 1.1667x; 1.1667x over previous
//
#include <hip/hip_runtime.h>
#include <math.h>

#define LQ 22223
#define NH 8
#define NL 4
#define NP 4
#define CDIM 256
#define MBLK 348              // ceil(LQ/64)
// XCD-swizzled block counts: groups of 8 (one per XCD), 44 row-tiles per XCD
#define NBV  (176 * 8)        // v-GEMM:   4 bx per by  -> j in [0,176)
#define NBOA (264 * 8)        // oa-GEMM:  6 bx per by  -> j in [0,264)

typedef __attribute__((ext_vector_type(8))) short short8;
typedef __attribute__((ext_vector_type(4))) float f32x4;

__device__ __forceinline__ ushort f2bf(float f) {
    union { float f; unsigned u; } c; c.f = f;
    unsigned u = c.u;
    return (ushort)((u + 0x7fffu + ((u >> 16) & 1u)) >> 16);   // RNE
}
__device__ __forceinline__ float bflo(unsigned u) {
    union { unsigned u; float f; } c; c.u = u << 16; return c.f;
}
__device__ __forceinline__ float bfhi(unsigned u) {
    union { unsigned u; float f; } c; c.u = u & 0xffff0000u; return c.f;
}

// ---------------------------------------------------------------------------
// Transpose+convert weights fp32 [K=256][N] -> bf16 [N][K].
// Wt_oa = concat(W_off rows, W_attn rows); bcat = concat(b_off, b_attn).
// ---------------------------------------------------------------------------
__global__ __launch_bounds__(256) void convert_wt(
    const float* __restrict__ Wv, const float* __restrict__ Wo,
    const float* __restrict__ Wu, const float* __restrict__ Wa,
    const float* __restrict__ bo, const float* __restrict__ ba,
    ushort* __restrict__ Tv, ushort* __restrict__ Toa,
    ushort* __restrict__ Tu, float* __restrict__ bcat)
{
    int idx = blockIdx.x * 256 + threadIdx.x;
    if (idx >= 229376) {
        int b = idx - 229376;
        if (b < 384) bcat[b] = (b < 256) ? bo[b] : ba[b - 256];
        return;
    }
    const float* W; ushort* T; int N; int local;
    if      (idx < 65536)  { W = Wv; T = Tv;          N = 256; local = idx; }
    else if (idx < 131072) { W = Wo; T = Toa;         N = 256; local = idx - 65536; }
    else if (idx < 196608) { W = Wu; T = Tu;          N = 256; local = idx - 131072; }
    else                   { W = Wa; T = Toa + 65536; N = 128; local = idx - 196608; }
    int k = local & 255;
    int n = local >> 8;
    T[n * 256 + k] = f2bf(W[k * N + n]);
}

// ---------------------------------------------------------------------------
// Fused dual GEMM, XCD-swizzled + LDS double-buffered.
//   blocks [0, NBV):  v_bf = bf16(value @ Wt_val^T + b_val)        N=256
//   blocks [NBV, ..): offattn = query @ Wt_oa^T + bcat   (fp32)    N=384
// Swizzle: xcd = b&7, j = b>>3; by = xcd + 8*(j/nbx), bx = j%nbx —
// all bx-tiles of one A-row-block land on ONE XCD, so A is fetched from
// HBM once per row-block instead of nbx times.
// Double buffer: prefetch tile k+1 into regs post-barrier, ds_write to the
// alternate LDS bank after the MFMAs -> one barrier per K-iter, global-load
// latency overlapped with compute.
// ---------------------------------------------------------------------------
__global__ __launch_bounds__(256, 5) void gemm_dual(
    const float* __restrict__ value, const ushort* __restrict__ Wtv,
    const float* __restrict__ bv, ushort* __restrict__ Cv,
    const float* __restrict__ query, const ushort* __restrict__ Wtoa,
    const float* __restrict__ boa, float* __restrict__ Coa)
{
    const int K = 256;
    __shared__ ushort As[2][64 * 40];
    __shared__ ushort Bs[2][64 * 40];

    int b = blockIdx.x;
    const float* A; const ushort* Bt; const float* bias;
    int N, bx, by; bool isv;
    const int xcd = b & 7;
    if (b < NBV) {
        isv = true;  A = value; Bt = Wtv;  bias = bv;  N = 256;
        const int j = b >> 3;
        bx = j & 3;  by = xcd + 8 * (j >> 2);
    } else {
        isv = false; A = query; Bt = Wtoa; bias = boa; N = 384;
        const int j = (b - NBV) >> 3;
        bx = j % 6;  by = xcd + 8 * (j / 6);
    }
    if (by >= MBLK) return;

    const int tid = threadIdx.x;
    const int w = tid >> 6;
    const int l = tid & 63;
    const int bm = by * 64;
    const int bn = bx * 64;

    const int r = tid >> 2;
    const int c = tid & 3;

    const int m_l  = (w << 4) + (l & 15);
    const int koff = (l >> 4) << 3;

    const bool arow_ok = (bm + r) < LQ;
    const float*  Ap = A  + (size_t)(bm + r) * K + c * 8;
    const ushort* Bp = Bt + (size_t)(bn + r) * K + c * 8;

    auto ldA = [&](int k0) -> short8 {
        short8 av = {0, 0, 0, 0, 0, 0, 0, 0};
        if (arow_ok) {
            const float4 f0 = *reinterpret_cast<const float4*>(Ap + k0);
            const float4 f1 = *reinterpret_cast<const float4*>(Ap + k0 + 4);
            av[0] = (short)f2bf(f0.x); av[1] = (short)f2bf(f0.y);
            av[2] = (short)f2bf(f0.z); av[3] = (short)f2bf(f0.w);
            av[4] = (short)f2bf(f1.x); av[5] = (short)f2bf(f1.y);
            av[6] = (short)f2bf(f1.z); av[7] = (short)f2bf(f1.w);
        }
        return av;
    };

    short8 av = ldA(0);
    short8 bvv = *reinterpret_cast<const short8*>(Bp);
    *reinterpret_cast<short8*>(&As[0][r * 40 + c * 8]) = av;
    *reinterpret_cast<short8*>(&Bs[0][r * 40 + c * 8]) = bvv;

    f32x4 acc[4] = {};

    #pragma unroll
    for (int k = 0; k < 8; ++k) {
        __syncthreads();
        if (k < 7) {
            av  = ldA((k + 1) * 32);
            bvv = *reinterpret_cast<const short8*>(Bp + (k + 1) * 32);
        }
        const int cur = k & 1;
        const short8 af = *reinterpret_cast<const short8*>(&As[cur][m_l * 40 + koff]);
        #pragma unroll
        for (int t = 0; t < 4; ++t) {
            const short8 bf = *reinterpret_cast<const short8*>(
                &Bs[cur][(t * 16 + (l & 15)) * 40 + koff]);
            acc[t] = __builtin_amdgcn_mfma_f32_16x16x32_bf16(af, bf, acc[t], 0, 0, 0);
        }
        if (k < 7) {
            const int nxt = cur ^ 1;
            *reinterpret_cast<short8*>(&As[nxt][r * 40 + c * 8]) = av;
            *reinterpret_cast<short8*>(&Bs[nxt][r * 40 + c * 8]) = bvv;
        }
    }

    const int row0 = bm + (w << 4) + ((l >> 4) << 2);
    #pragma unroll
    for (int t = 0; t < 4; ++t) {
        const int col = bn + t * 16 + (l & 15);
        const float bs = bias[col];
        #pragma unroll
        for (int i = 0; i < 4; ++i) {
            const int row = row0 + i;
            if (row < LQ) {
                const float o = acc[t][i] + bs;
                if (isv) Cv[(size_t)row * 256 + col] = f2bf(o);
                else     Coa[(size_t)row * 384 + col] = o;
            }
        }
    }
}

// ---------------------------------------------------------------------------
// Output GEMM (bf16 A), same swizzle + double buffer. N=256, fp32 out.
// ---------------------------------------------------------------------------
__global__ __launch_bounds__(256, 5) void gemm_out(
    const ushort* __restrict__ A, const ushort* __restrict__ Bt,
    const float* __restrict__ bias, float* __restrict__ C)
{
    const int K = 256, N = 256;
    __shared__ ushort As[2][64 * 40];
    __shared__ ushort Bs[2][64 * 40];

    const int b = blockIdx.x;
    const int xcd = b & 7;
    const int j = b >> 3;
    const int bx = j & 3;
    const int by = xcd + 8 * (j >> 2);
    if (by >= MBLK) return;

    const int tid = threadIdx.x;
    const int w = tid >> 6;
    const int l = tid & 63;
    const int bm = by * 64;
    const int bn = bx * 64;

    const int r = tid >> 2;
    const int c = tid & 3;

    const int m_l  = (w << 4) + (l & 15);
    const int koff = (l >> 4) << 3;

    const bool arow_ok = (bm + r) < LQ;
    const ushort* Ap = A  + (size_t)(bm + r) * K + c * 8;
    const ushort* Bp = Bt + (size_t)(bn + r) * K + c * 8;

    auto ldA = [&](int k0) -> short8 {
        short8 av = {0, 0, 0, 0, 0, 0, 0, 0};
        if (arow_ok) av = *reinterpret_cast<const short8*>(Ap + k0);
        return av;
    };

    short8 av = ldA(0);
    short8 bvv = *reinterpret_cast<const short8*>(Bp);
    *reinterpret_cast<short8*>(&As[0][r * 40 + c * 8]) = av;
    *reinterpret_cast<short8*>(&Bs[0][r * 40 + c * 8]) = bvv;

    f32x4 acc[4] = {};

    #pragma unroll
    for (int k = 0; k < 8; ++k) {
        __syncthreads();
        if (k < 7) {
            av  = ldA((k + 1) * 32);
            bvv = *reinterpret_cast<const short8*>(Bp + (k + 1) * 32);
        }
        const int cur = k & 1;
        const short8 af = *reinterpret_cast<const short8*>(&As[cur][m_l * 40 + koff]);
        #pragma unroll
        for (int t = 0; t < 4; ++t) {
            const short8 bf = *reinterpret_cast<const short8*>(
                &Bs[cur][(t * 16 + (l & 15)) * 40 + koff]);
            acc[t] = __builtin_amdgcn_mfma_f32_16x16x32_bf16(af, bf, acc[t], 0, 0, 0);
        }
        if (k < 7) {
            const int nxt = cur ^ 1;
            *reinterpret_cast<short8*>(&As[nxt][r * 40 + c * 8]) = av;
            *reinterpret_cast<short8*>(&Bs[nxt][r * 40 + c * 8]) = bvv;
        }
    }

    const int row0 = bm + (w << 4) + ((l >> 4) << 2);
    #pragma unroll
    for (int t = 0; t < 4; ++t) {
        const int col = bn + t * 16 + (l & 15);
        const float bs = bias[col];
        #pragma unroll
        for (int i = 0; i < 4; ++i) {
            const int row = row0 + i;
            if (row < LQ) C[(size_t)row * N + col] = acc[t][i] + bs;
        }
    }
}

// ---------------------------------------------------------------------------
// In-place softmax over 16 logits per (q,h) at offattn + q*384 + 256 + h*16.
// (Separate kernel: round 6 showed folding it into the sampler costs ~27 µs
// in redundant logit reads + serialized phase-1 latency.)
// ---------------------------------------------------------------------------
__global__ __launch_bounds__(256) void softmax16(float* __restrict__ offattn, int rows)
{
    const int r = blockIdx.x * 256 + threadIdx.x;
    if (r >= rows) return;
    const int q = r >> 3;
    const int h = r & 7;
    float4* p = reinterpret_cast<float4*>(offattn + (size_t)q * 384 + 256 + h * 16);
    float v[16];
    #pragma unroll
    for (int i = 0; i < 4; ++i) {
        const float4 f = p[i];
        v[i * 4 + 0] = f.x; v[i * 4 + 1] = f.y; v[i * 4 + 2] = f.z; v[i * 4 + 3] = f.w;
    }
    float m = v[0];
    #pragma unroll
    for (int i = 1; i < 16; ++i) m = fmaxf(m, v[i]);
    float s = 0.f;
    #pragma unroll
    for (int i = 0; i < 16; ++i) { v[i] = expf(v[i] - m); s += v[i]; }
    const float inv = 1.f / s;
    #pragma unroll
    for (int i = 0; i < 4; ++i)
        p[i] = make_float4(v[i * 4 + 0] * inv, v[i * 4 + 1] * inv,
                           v[i * 4 + 2] * inv, v[i * 4 + 3] * inv);
}

// ---------------------------------------------------------------------------
// Multi-scale deformable sampling over bf16 value.
//   block = 64 q x 4 lanes (8 bf16 channels each), one head.
//   blockIdx.x = qg*8 + h -> head-pinned to XCDs (per-head slice 1.42 MB).
// Phase 1 (unrolled, cheap): reads SOFTMAXED weights (4 B/task).
// Phase 2: unroll 4 (16 gathers in flight) + __launch_bounds__(256,5)
//   (VGPR <= 102, LDS 32 KB -> 5 blocks/CU = 20 waves/CU). Outstanding-load
//   model: need W*I ~ 200/CU to cover ~335 cyc avg gather latency.
// ---------------------------------------------------------------------------
__global__ __launch_bounds__(256, 5) void msda_sample(
    const ushort* __restrict__ v, const float* __restrict__ offattn,
    const float* __restrict__ ref, ushort* __restrict__ outp)
{
    __shared__ int4   s_off[1024];   // [p*64 + qi], element offsets into v
    __shared__ float4 s_wts[1024];

    const int h = blockIdx.x & 7;
    const int qbase = (blockIdx.x >> 3) * 64;
    const int tid = threadIdx.x;

    const int Hs[4] = {100, 50, 25, 13};
    const int Ws[4] = {167, 84, 42, 21};
    const int starts[4] = {0, 16700, 20900, 21950};
    const int h32 = h * 32;

    // ---- Phase 1 ----
    #pragma unroll
    for (int t2 = 0; t2 < 4; ++t2) {
        const int t = t2 * 256 + tid;     // = pi*64 + qi
        const int qi = t & 63;
        const int pi = t >> 6;            // 0..15
        const int q = qbase + qi;
        if (q < LQ) {
            const int l = pi >> 2;
            const int W = Ws[l], H = Hs[l];
            const float* refq = ref + (size_t)q * (NL * 4) + l * 4;
            const float cx = refq[0], cy = refq[1], rw = refq[2], rh = refq[3];
            const float* row = offattn + (size_t)q * 384;
            const float ox  = row[h32 + pi * 2];
            const float oy  = row[h32 + pi * 2 + 1];
            const float wgt = row[256 + h * 16 + pi];

            const float lx = cx + ox * 0.125f * rw;
            const float ly = cy + oy * 0.125f * rh;
            const float x = lx * (float)W - 0.5f;
            const float y = ly * (float)H - 0.5f;

            const float x0f = floorf(x);
            const float y0f = floorf(y);
            const int x0 = (int)x0f, y0 = (int)y0f;
            const float wx1 = x - x0f, wy1 = y - y0f;
            const float wx0 = 1.f - wx1, wy0 = 1.f - wy1;

            const bool xv0 = (x0 >= 0) && (x0 < W);
            const bool xv1 = (x0 + 1 >= 0) && (x0 + 1 < W);
            const bool yv0 = (y0 >= 0) && (y0 < H);
            const bool yv1 = (y0 + 1 >= 0) && (y0 + 1 < H);

            const int x0c = min(max(x0, 0), W - 1);
            const int x1c = min(max(x0 + 1, 0), W - 1);
            const int y0c = min(max(y0, 0), H - 1);
            const int y1c = min(max(y0 + 1, 0), H - 1);

            int4 ob;
            ob.x = ((starts[l] + y0c * W + x0c) << 8) + h32;
            ob.y = ((starts[l] + y0c * W + x1c) << 8) + h32;
            ob.z = ((starts[l] + y1c * W + x0c) << 8) + h32;
            ob.w = ((starts[l] + y1c * W + x1c) << 8) + h32;
            float4 wb;
            wb.x = (xv0 && yv0) ? wgt * wy0 * wx0 : 0.f;
            wb.y = (xv1 && yv0) ? wgt * wy0 * wx1 : 0.f;
            wb.z = (xv0 && yv1) ? wgt * wy1 * wx0 : 0.f;
            wb.w = (xv1 && yv1) ? wgt * wy1 * wx1 : 0.f;
            s_off[t] = ob;
            s_wts[t] = wb;
        }
    }
    __syncthreads();

    // ---- Phase 2 ----
    const int qi = tid >> 2;          // 0..63
    const int dg = tid & 3;           // channel group (8 bf16)
    const int q = qbase + qi;
    if (q >= LQ) return;
    const int d8 = dg * 8;

    float acc[8] = {};

    #pragma unroll 4
    for (int p = 0; p < 16; ++p) {
        const int4   o = s_off[p * 64 + qi];
        const float4 w = s_wts[p * 64 + qi];
        const uint4 a0 = *reinterpret_cast<const uint4*>(v + o.x + d8);
        const uint4 a1 = *reinterpret_cast<const uint4*>(v + o.y + d8);
        const uint4 a2 = *reinterpret_cast<const uint4*>(v + o.z + d8);
        const uint4 a3 = *reinterpret_cast<const uint4*>(v + o.w + d8);
        const unsigned u0[4] = {a0.x, a0.y, a0.z, a0.w};
        const unsigned u1[4] = {a1.x, a1.y, a1.z, a1.w};
        const unsigned u2[4] = {a2.x, a2.y, a2.z, a2.w};
        const unsigned u3[4] = {a3.x, a3.y, a3.z, a3.w};
        #pragma unroll
        for (int j = 0; j < 4; ++j) {
            acc[2 * j]     += w.x * bflo(u0[j]) + w.y * bflo(u1[j])
                            + w.z * bflo(u2[j]) + w.w * bflo(u3[j]);
            acc[2 * j + 1] += w.x * bfhi(u0[j]) + w.y * bfhi(u1[j])
                            + w.z * bfhi(u2[j]) + w.w * bfhi(u3[j]);
        }
    }

    short8 o8;
    #pragma unroll
    for (int j = 0; j < 8; ++j) o8[j] = (short)f2bf(acc[j]);
    *reinterpret_cast<short8*>(outp + (size_t)q * CDIM + h32 + d8) = o8;
}

// ---------------------------------------------------------------------------
extern "C" void kernel_launch(void* const* d_in, const int* in_sizes, int n_in,
                              void* d_out, int out_size, void* d_ws, size_t ws_size,
                              hipStream_t stream)
{
    const float* query  = (const float*)d_in[0];
    const float* ref    = (const float*)d_in[1];
    const float* value  = (const float*)d_in[2];
    const float* W_off  = (const float*)d_in[3];
    const float* b_off  = (const float*)d_in[4];
    const float* W_attn = (const float*)d_in[5];
    const float* b_attn = (const float*)d_in[6];
    const float* W_val  = (const float*)d_in[7];
    const float* b_val  = (const float*)d_in[8];
    const float* W_out  = (const float*)d_in[9];
    const float* b_out  = (const float*)d_in[10];
    float* out = (float*)d_out;

    char* p = (char*)d_ws;
    ushort* v_bf    = (ushort*)p; p += (size_t)LQ * CDIM * 2;   // bf16 value'
    float*  offattn = (float*)p;  p += (size_t)LQ * 384 * 4;
    ushort* outp    = (ushort*)p; p += (size_t)LQ * CDIM * 2;   // bf16 sampled
    ushort* Wt_val  = (ushort*)p; p += 65536 * 2;
    ushort* Wt_oa   = (ushort*)p; p += (65536 + 32768) * 2;
    ushort* Wt_out  = (ushort*)p; p += 65536 * 2;
    float*  bcat    = (float*)p;  p += 384 * 4;

    // 1. weights fp32 -> bf16 [N][K] (+ concatenated off/attn bias)
    convert_wt<<<(229376 + 384 + 255) / 256, 256, 0, stream>>>(
        W_val, W_off, W_out, W_attn, b_off, b_attn, Wt_val, Wt_oa, Wt_out, bcat);

    // 2. fused: v_bf = bf16(value@Wv + bv)  AND  offattn = query@Woa + bcat
    gemm_dual<<<NBV + NBOA, 256, 0, stream>>>(
        value, Wt_val, b_val, v_bf, query, Wt_oa, bcat, offattn);

    // 3. softmax over 16 per (q,h)
    softmax16<<<(LQ * NH + 255) / 256, 256, 0, stream>>>(offattn, LQ * NH);

    // 4. deformable sampling -> outp (bf16)
    const int qg = (LQ + 63) / 64;    // 348
    msda_sample<<<qg * 8, 256, 0, stream>>>(v_bf, offattn, ref, outp);

    // 5. out = outp @ W_out + b_out
    gemm_out<<<176 * 8, 256, 0, stream>>>(outp, Wt_out, b_out, out);
}